// Round 1
// 2963.671 us; speedup vs baseline: 1.4087x; 1.4087x over previous
//
#include <hip/hip_runtime.h>
#include <hip/hip_bf16.h>

// LSTM B=64 S=512 I=H=1024.
// Phase 1: xg = x @ W_ih^T + bias (bf16 MFMA GEMM, unchanged - verified).
// Phase 2 (restructured this round): batch-grouped persistent recurrence.
//   Recurrence is independent per batch row -> 4 independent groups of 32
//   blocks; group g owns batches [16g,16g+16). Block owns 32 hidden cols
//   (128 gate rows) for its group's 16 batches. Same W_hh VGPR budget as
//   before (8 waves x 16 rows x 1024 K), but:
//     - staged h per block: 128 KB -> 32 KB  (4x less LLC traffic/latency)
//     - barrier fan-in: 128 -> 32, groups fully decoupled (own counters)
//     - H/C HBM stores deferred to next-step top, drained with counted
//       vmcnt(2) so HBM write-ack never sits on the sync critical path.
//   Sync protocol itself (relaxed agent atomics, vmcnt drain, counter spin)
//   is byte-identical to the verified kernel, just per-group.

#define GROUPS 4
#define BPG 32

typedef __bf16 bf16x8 __attribute__((ext_vector_type(8)));
typedef float f32x4 __attribute__((ext_vector_type(4)));

__device__ __forceinline__ unsigned short f2b(float f) {
  unsigned u = __builtin_bit_cast(unsigned, f);
  u += 0x7fffu + ((u >> 16) & 1u);
  return (unsigned short)(u >> 16);
}
__device__ __forceinline__ float b2f(unsigned short s) {
  return __builtin_bit_cast(float, (unsigned)s << 16);
}
__device__ __forceinline__ float sigmoidf_(float z) { return 1.f / (1.f + __expf(-z)); }
__device__ __forceinline__ float tanh_fast(float z) {
  z = fminf(15.f, fmaxf(-15.f, z));
  float e2 = __expf(2.f * z);
  return (e2 - 1.f) / (e2 + 1.f);
}

template <int AUX>
__device__ __forceinline__ void g2l16(const unsigned short* gp, unsigned short* lp) {
  auto g1 = reinterpret_cast<__attribute__((address_space(1))) unsigned short*>(
      reinterpret_cast<unsigned long long>(gp));
  auto l3 = reinterpret_cast<__attribute__((address_space(3))) unsigned short*>(
      reinterpret_cast<unsigned long long>(lp));
  __builtin_amdgcn_global_load_lds(g1, l3, 16, 0, AUX);
}

__global__ __launch_bounds__(256) void cvt_bf16_k(const float* __restrict__ src,
                                                  unsigned short* __restrict__ dst, int n4) {
  int i = blockIdx.x * 256 + threadIdx.x;
  if (i >= n4) return;
  float4 v = reinterpret_cast<const float4*>(src)[i];
  ushort4 o;
  o.x = f2b(v.x); o.y = f2b(v.y); o.z = f2b(v.z); o.w = f2b(v.w);
  reinterpret_cast<ushort4*>(dst)[i] = o;
}

__global__ __launch_bounds__(256) void bias_k(const float* __restrict__ a,
                                              const float* __restrict__ b,
                                              float* __restrict__ o) {
  int i = blockIdx.x * 256 + threadIdx.x;
  if (i < 4096) o[i] = a[i] + b[i];
}

// xg GEMM (unchanged, correctness-verified)
__global__ __launch_bounds__(256) void gemm_xg_k(const float* __restrict__ X,
                                                 const unsigned short* __restrict__ Wb,
                                                 const float* __restrict__ bias,
                                                 unsigned short* __restrict__ xg) {
  __shared__ __align__(16) unsigned short As[128 * 32];
  __shared__ __align__(16) unsigned short Bs[128 * 32];
  const int tid = threadIdx.x;
  const int w = tid >> 6, l = tid & 63;
  const int rowBase = blockIdx.y * 128;
  const int colBase = blockIdx.x * 128;
  const int wm = w & 1, wn = w >> 1;
  f32x4 acc[4][4] = {};

  for (int kt = 0; kt < 32; ++kt) {
    __syncthreads();
    const int k0 = kt * 32;
#pragma unroll
    for (int p = 0; p < 2; ++p) {
      int c = p * 4 + w;
      const unsigned short* gp = Wb + (colBase + c * 16 + (l >> 2)) * 1024 + k0 + (l & 3) * 8;
      g2l16<0>(gp, &Bs[c * 512]);
    }
#pragma unroll
    for (int i = 0; i < 4; ++i) {
      int idx = tid + i * 256;
      int r = idx >> 3;
      int cc = (idx & 7) * 4;
      const float4 v = *reinterpret_cast<const float4*>(X + (long)(rowBase + r) * 1024 + k0 + cc);
      uint2 u;
      u.x = ((unsigned)f2b(v.y) << 16) | (unsigned)f2b(v.x);
      u.y = ((unsigned)f2b(v.w) << 16) | (unsigned)f2b(v.z);
      *reinterpret_cast<uint2*>(&As[r * 32 + cc]) = u;
    }
    __syncthreads();
    bf16x8 af[4], bfr[4];
#pragma unroll
    for (int mt = 0; mt < 4; ++mt)
      af[mt] = *reinterpret_cast<const bf16x8*>(&As[(wm * 64 + mt * 16 + (l & 15)) * 32 + (l >> 4) * 8]);
#pragma unroll
    for (int nt = 0; nt < 4; ++nt)
      bfr[nt] = *reinterpret_cast<const bf16x8*>(&Bs[(wn * 64 + nt * 16 + (l & 15)) * 32 + (l >> 4) * 8]);
#pragma unroll
    for (int mt = 0; mt < 4; ++mt)
#pragma unroll
      for (int nt = 0; nt < 4; ++nt)
        acc[mt][nt] = __builtin_amdgcn_mfma_f32_16x16x32_bf16(af[mt], bfr[nt], acc[mt][nt], 0, 0, 0);
  }
#pragma unroll
  for (int nt = 0; nt < 4; ++nt) {
    int n = colBase + wn * 64 + nt * 16 + (l & 15);
    float bv = bias[n];
#pragma unroll
    for (int mt = 0; mt < 4; ++mt) {
      int m0 = rowBase + wm * 64 + mt * 16 + (l >> 4) * 4;
#pragma unroll
      for (int r = 0; r < 4; ++r)
        xg[(long)(m0 + r) * 4096 + n] = f2b(acc[mt][nt][r] + bv);
    }
  }
}

// Persistent recurrence: 4 groups x 32 blocks x 512 threads.
// Group grp = blockIdx>>5 owns batches [16*grp, 16*grp+16).
// Block owns hidden cols [col0, col0+32)  (= 128 gate rows) for its group.
__global__ __launch_bounds__(512, 2) void lstm_rec_k(const unsigned short* __restrict__ Whb,
                                                     const unsigned short* __restrict__ xg,
                                                     unsigned short* __restrict__ hbuf,
                                                     int* __restrict__ cnt,
                                                     float* __restrict__ out) {
  // h rows padded +8 shorts: stride 516 dw == 4 mod 32 (2-way LDS access, free)
  __shared__ __align__(16) unsigned short hL[16 * 1032];   // 33 KB staged group-h
  __shared__ float gS[16][132];                            // 8.4 KB, 132 == 4 mod 32
  __shared__ __align__(16) unsigned short hS[16][32];      // 1 KB

  const int tid = threadIdx.x;
  const int w = tid >> 6, l = tid & 63;
  const int grp = blockIdx.x >> 5;          // batch group
  const int col0 = (blockIdx.x & 31) * 32;  // owned hidden-col slice
  const int b0 = grp * 16;                  // first batch of group
  int* cg = cnt + grp * 512;                // per-group counters (own lines)

  // W_hh slab -> regs. Wave w owns block-rows [w*16, w*16+16) of the 128-row
  // slab. Block-row n (0..127) <-> global gate row (n>>5)*1024 + col0 + (n&31).
  bf16x8 warr[32];
  {
    int n = w * 16 + (l & 15);
    const unsigned short* wp =
        Whb + (unsigned)((n >> 5) * 1024 + col0 + (n & 31)) * 1024 + (l >> 4) * 8;
#pragma unroll
    for (int kt = 0; kt < 32; ++kt)
      warr[kt] = *reinterpret_cast<const bf16x8*>(wp + kt * 32);
  }

  float c = 0.f;
  float hnP = 0.f;   // deferred H-output value (step t-1)
  int oidxP = 0;     // deferred output index
  const int eb = tid >> 5, ec = tid & 31;   // epilogue: (group-local batch, col)
  const int arow = l & 15;                  // MFMA A row = group-local batch
  float* Hout = out;
  float* Cout = out + 33554432;

  for (int t = 0; t < 512; ++t) {
    const unsigned short* hcur = hbuf + (t & 1) * 65536 + b0 * 1024;
    // Stage group's h (16x1024 bf16 = 32 KB): 32 x 1KB chunks, LLC-coherent
#pragma unroll
    for (int j = 0; j < 4; ++j) {
      int ch = w * 4 + j;
      int r = ch >> 1, hf = ch & 1;
      g2l16<0x11>(hcur + r * 1024 + hf * 512 + l * 8, &hL[r * 1032 + hf * 512 + l * 8]);
    }
    // xg prefetch for this step's epilogue (normal cached loads)
    const unsigned short* xp = xg + (((b0 + eb) << 9) + t) * 4096 + col0 + ec;
    unsigned short x0 = xp[0], x1 = xp[1024], x2 = xp[2048], x3 = xp[3072];
    // Deferred H/C stores for step t-1: issued as the 2 YOUNGEST vmem ops,
    // then counted wait drains only the 8 staging/xg loads. HBM write-ack
    // drains in the background during MFMA+epilogue+barrier.
    __builtin_amdgcn_sched_barrier(0);
    if (t) {
      Hout[oidxP] = hnP;
      Cout[oidxP] = c;   // c still holds c(t-1) here
      __builtin_amdgcn_sched_barrier(0);
      asm volatile("s_waitcnt vmcnt(2)" ::: "memory");
    } else {
      asm volatile("s_waitcnt vmcnt(0)" ::: "memory");
    }
    __builtin_amdgcn_sched_barrier(0);
    __syncthreads();

    // gates = h @ W_hh-slab^T : two accumulator chains (16 dependent MFMAs each)
    f32x4 acc0 = {0.f, 0.f, 0.f, 0.f}, acc1 = {0.f, 0.f, 0.f, 0.f};
#pragma unroll
    for (int kt = 0; kt < 32; kt += 2) {
      bf16x8 a0 = *reinterpret_cast<const bf16x8*>(&hL[arow * 1032 + kt * 32 + (l >> 4) * 8]);
      bf16x8 a1 = *reinterpret_cast<const bf16x8*>(&hL[arow * 1032 + (kt + 1) * 32 + (l >> 4) * 8]);
      acc0 = __builtin_amdgcn_mfma_f32_16x16x32_bf16(a0, warr[kt], acc0, 0, 0, 0);
      acc1 = __builtin_amdgcn_mfma_f32_16x16x32_bf16(a1, warr[kt + 1], acc1, 0, 0, 0);
    }
    f32x4 acc = acc0 + acc1;
#pragma unroll
    for (int r = 0; r < 4; ++r)
      gS[(l >> 4) * 4 + r][w * 16 + (l & 15)] = acc[r];
    __syncthreads();

    float zi = gS[eb][ec]      + b2f(x0);
    float zf = gS[eb][32 + ec] + b2f(x1);
    float zg = gS[eb][64 + ec] + b2f(x2);
    float zo = gS[eb][96 + ec] + b2f(x3);
    float ig = sigmoidf_(zi), fg = sigmoidf_(zf), og = sigmoidf_(zo);
    float gg = tanh_fast(zg);
    c = fg * c + ig * gg;
    float hn = og * tanh_fast(c);
    hS[eb][ec] = f2b(hn);
    hnP = hn;
    oidxP = ((b0 + eb) << 19) + (t << 10) + col0 + ec;
    __syncthreads();

    if (t < 511) {
      unsigned short* hnx = hbuf + ((t + 1) & 1) * 65536;
      if (tid < 128) {
        int b = tid >> 3, sg = tid & 7;
        unsigned long long v = *reinterpret_cast<const unsigned long long*>(&hS[b][sg * 4]);
        __hip_atomic_store(
            reinterpret_cast<unsigned long long*>(hnx + (b0 + b) * 1024 + col0 + sg * 4),
            v, __ATOMIC_RELAXED, __HIP_MEMORY_SCOPE_AGENT);
      }
      if (w < 2) asm volatile("s_waitcnt vmcnt(0)" ::: "memory");  // only storing waves drain
      __syncthreads();                                             // -> h slice at LLC
      if (tid == 0) {
        __hip_atomic_fetch_add(&cg[t], 1, __ATOMIC_RELAXED, __HIP_MEMORY_SCOPE_AGENT);
        while (__hip_atomic_load(&cg[t], __ATOMIC_RELAXED, __HIP_MEMORY_SCOPE_AGENT) < BPG)
          __builtin_amdgcn_s_sleep(2);
      }
      __syncthreads();
    }
  }
  Hout[oidxP] = hnP;   // final step's deferred outputs
  Cout[oidxP] = c;
}

extern "C" void kernel_launch(void* const* d_in, const int* in_sizes, int n_in,
                              void* d_out, int out_size, void* d_ws, size_t ws_size,
                              hipStream_t stream) {
  const float* x    = (const float*)d_in[0];
  const float* W_ih = (const float*)d_in[1];
  const float* W_hh = (const float*)d_in[2];
  const float* b_ih = (const float*)d_in[3];
  const float* b_hh = (const float*)d_in[4];

  char* ws = (char*)d_ws;
  int* cnt             = (int*)ws;                         // 8 KB: 4 groups x 512 counters
  unsigned short* hbuf = (unsigned short*)(ws + 8192);     // 2 x 64x1024 bf16 (256 KB)
  float* biasS         = (float*)(ws + 270336);            // 4096 f32
  unsigned short* Wihb = (unsigned short*)(ws + 286720);   // 8 MB bf16
  unsigned short* Whhb = (unsigned short*)(ws + 8675328);  // 8 MB bf16
  unsigned short* xgb  = (unsigned short*)(ws + 17063936); // 268 MB bf16 [32768][4096]
  float* out = (float*)d_out;

  (void)hipMemsetAsync(ws, 0, 270336, stream);             // zero counters + h0
  cvt_bf16_k<<<4096, 256, 0, stream>>>(W_ih, Wihb, 1048576);
  cvt_bf16_k<<<4096, 256, 0, stream>>>(W_hh, Whhb, 1048576);
  bias_k<<<16, 256, 0, stream>>>(b_ih, b_hh, biasS);
  gemm_xg_k<<<dim3(32, 256), 256, 0, stream>>>(x, Wihb, biasS, xgb);
  lstm_rec_k<<<GROUPS * BPG, 512, 0, stream>>>(Whhb, xgb, hbuf, cnt, out);
}